// Round 1
// baseline (865.333 us; speedup 1.0000x reference)
//
#include <hip/hip_runtime.h>
#include <math.h>

typedef __bf16 bf16x8 __attribute__((ext_vector_type(8)));
typedef float  f32x4  __attribute__((ext_vector_type(4)));

__device__ __forceinline__ float gelu_f(float x) {
  const float k0 = 0.7978845608028654f;
  const float k1 = 0.044715f;
  float x3 = x * x * x;
  return 0.5f * x * (1.0f + tanhf(k0 * (x + k1 * x3)));
}

// ---------------- mean pool over seq: (128,512,1024) -> (128,1024) ----------------
__global__ __launch_bounds__(256) void pool_kernel(
    const float* __restrict__ xe, float* __restrict__ xpf, __bf16* __restrict__ xpb) {
  int b = blockIdx.y;
  int c = blockIdx.x * 256 + threadIdx.x;
  const float* p = xe + (size_t)b * 512 * 1024 + c;
  float s = 0.f;
#pragma unroll 8
  for (int i = 0; i < 512; ++i) s += p[(size_t)i * 1024];
  s *= (1.f / 512.f);
  xpf[b * 1024 + c] = s;
  xpb[b * 1024 + c] = (__bf16)s;
}

// ---------------- batched transpose fp32 -> bf16 (weights stored N x K) ----------------
__global__ __launch_bounds__(256) void transpose_batch(
    const float* __restrict__ Wpi, const float* __restrict__ Wpa,
    const float* __restrict__ Wc,  const float* __restrict__ w1f,
    const float* __restrict__ w2f, const float* __restrict__ wo,
    __bf16* __restrict__ WpiT, __bf16* __restrict__ WpaT,
    __bf16* __restrict__ WcaT, __bf16* __restrict__ WcbT, __bf16* __restrict__ WccT,
    __bf16* __restrict__ w1T,  __bf16* __restrict__ w2T,  __bf16* __restrict__ woT)
{
  int bid = blockIdx.x;
  const float* src; __bf16* dst; int R, C;
  if      (bid < 512)  {              src = Wpi;              dst = WpiT;            R = 1024; C = 512;  }
  else if (bid < 640)  { bid -= 512;  src = Wpa;              dst = WpaT;            R = 256;  C = 512;  }
  else if (bid < 896)  { bid -= 640;  src = Wc;               dst = WcaT;            R = 512;  C = 512;  }
  else if (bid < 1152) { bid -= 896;  src = Wc + 512*512;     dst = WcbT;            R = 512;  C = 512;  }
  else if (bid < 1408) { bid -= 1152; src = Wc + 1024*512;    dst = WccT;            R = 512;  C = 512;  }
  else if (bid < 2432) { bid -= 1408; src = w1f;              dst = w1T;             R = 512;  C = 2048; }
  else if (bid < 3456) { bid -= 2432; src = w1f + 512*2048;   dst = w1T + 1048576;   R = 512;  C = 2048; }
  else if (bid < 4480) { bid -= 3456; src = w2f;              dst = w2T;             R = 2048; C = 512;  }
  else if (bid < 5504) { bid -= 4480; src = w2f + 2048*512;   dst = w2T + 1048576;   R = 2048; C = 512;  }
  else if (bid < 5760) { bid -= 5504; src = wo;               dst = woT;             R = 512;  C = 512;  }
  else                 { bid -= 5760; src = wo + 512*512;     dst = woT + 512*512;   R = 512;  C = 512;  }

  int nbc = C / 32;
  int r0 = (bid / nbc) * 32;
  int c0 = (bid % nbc) * 32;

  __shared__ float t[32][33];
  int tx = threadIdx.x & 31, ty = threadIdx.x >> 5;
#pragma unroll
  for (int i = 0; i < 32; i += 8)
    t[ty + i][tx] = src[(size_t)(r0 + ty + i) * C + c0 + tx];
  __syncthreads();
#pragma unroll
  for (int i = 0; i < 32; i += 8)
    dst[(size_t)(c0 + ty + i) * R + r0 + tx] = (__bf16)t[tx][ty + i];
}

// ---------------- misc: pack V-slice of wqkv to bf16, y to bf16, zero z ----------------
__global__ __launch_bounds__(256) void misc_convert(
    const float* __restrict__ wqkv, const float* __restrict__ y,
    __bf16* __restrict__ Wvb, __bf16* __restrict__ yb,
    float* __restrict__ zf, __bf16* __restrict__ zb)
{
  int i = blockIdx.x * 256 + threadIdx.x;
  if (i < 524288) {
    int l = i >> 18, rem = i & 262143;
    int m = rem >> 9, k = rem & 511;
    Wvb[i] = (__bf16)wqkv[(size_t)l * 512 * 1536 + (size_t)m * 1536 + 1024 + k];
  } else if (i < 557056) {
    int j = i - 524288; yb[j] = (__bf16)y[j];
  } else if (i < 622592) {
    zf[i - 557056] = 0.f;
  } else if (i < 688128) {
    zb[i - 622592] = (__bf16)0.f;
  }
}

// ---------------- beff[l] = bv @ wo + bo ----------------
__global__ __launch_bounds__(256) void beff_kernel(
    const float* __restrict__ bqkv, const float* __restrict__ wo,
    const float* __restrict__ bo, float* __restrict__ beff)
{
  int l = blockIdx.y;
  int n = blockIdx.x * 256 + threadIdx.x;
  const float* bv = bqkv + l * 1536 + 1024;
  const float* w  = wo + (size_t)l * 512 * 512;
  float s = bo[l * 512 + n];
#pragma unroll 8
  for (int k = 0; k < 512; ++k) s += bv[k] * w[(size_t)k * 512 + n];
  beff[l * 512 + n] = s;
}

// ---------------- fused MFMA GEMM stage ----------------
// out = epilogue( [LN(A)] @ B ),  A: MxK bf16 row-major, Bt: NxK bf16 row-major.
// epilogue: +bias[col], +resid[row,col], gelu, accum-into-outf, write outf (f32) / outb (bf16)
template<bool LN, bool GELU, bool RESID, bool ACCUM, bool BIAS, bool OUTF, bool OUTB, bool TROUT>
__global__ __launch_bounds__(256) void gemm_stage(
    const __bf16* __restrict__ A, const __bf16* __restrict__ Bt,
    const float* __restrict__ lng, const float* __restrict__ lnb,
    const float* __restrict__ bias, const float* __restrict__ resid,
    float* __restrict__ outf, __bf16* __restrict__ outb,
    int M, int N, int K)
{
  const int tid = threadIdx.x;
  const int bn0 = blockIdx.x * 64;
  const int bm0 = blockIdx.y * 64;

  __shared__ __bf16 Al[64][72];
  __shared__ __bf16 Bl[64][72];

  const int sr = tid >> 2;         // staging row (A rows / Bt rows)
  const int sc = (tid & 3) << 4;   // staging col within 64-wide K chunk

  float mu = 0.f, rs = 0.f;
  if (LN) {
    int chunk = K >> 2;
    const __bf16* ap = A + (size_t)(bm0 + sr) * K + (tid & 3) * chunk;
    float s = 0.f, s2 = 0.f;
    for (int i = 0; i < chunk; i += 8) {
      bf16x8 v = *(const bf16x8*)(ap + i);
#pragma unroll
      for (int j = 0; j < 8; ++j) { float f = (float)v[j]; s += f; s2 += f * f; }
    }
    s  += __shfl_xor(s, 1);  s2 += __shfl_xor(s2, 1);
    s  += __shfl_xor(s, 2);  s2 += __shfl_xor(s2, 2);
    mu = s / (float)K;
    rs = rsqrtf(s2 / (float)K - mu * mu + 1e-5f);
  }

  const int wave = tid >> 6, lane = tid & 63;
  const int wm = wave >> 1, wn = wave & 1;
  const int lr = lane & 15;
  const int lk = (lane >> 4) << 3;

  f32x4 acc[2][2] = {};

  const int nkt = K >> 6;
  for (int kt = 0; kt < nkt; ++kt) {
    const int k0 = kt << 6;
    {
      const __bf16* gp = A + (size_t)(bm0 + sr) * K + k0 + sc;
      bf16x8 v0 = *(const bf16x8*)gp;
      bf16x8 v1 = *(const bf16x8*)(gp + 8);
      if (LN) {
        const float* gg = lng + k0 + sc;
        const float* bb = lnb + k0 + sc;
#pragma unroll
        for (int j = 0; j < 8; ++j) {
          v0[j] = (__bf16)(((float)v0[j] - mu) * rs * gg[j] + bb[j]);
          v1[j] = (__bf16)(((float)v1[j] - mu) * rs * gg[j + 8] + bb[j + 8]);
        }
      }
      *(bf16x8*)&Al[sr][sc]     = v0;
      *(bf16x8*)&Al[sr][sc + 8] = v1;
    }
    {
      const __bf16* gp = Bt + (size_t)(bn0 + sr) * K + k0 + sc;
      *(bf16x8*)&Bl[sr][sc]     = *(const bf16x8*)gp;
      *(bf16x8*)&Bl[sr][sc + 8] = *(const bf16x8*)(gp + 8);
    }
    __syncthreads();
#pragma unroll
    for (int kc = 0; kc < 2; ++kc) {
      bf16x8 a0 = *(const bf16x8*)&Al[wm * 32 + lr     ][kc * 32 + lk];
      bf16x8 a1 = *(const bf16x8*)&Al[wm * 32 + 16 + lr][kc * 32 + lk];
      bf16x8 b0 = *(const bf16x8*)&Bl[wn * 32 + lr     ][kc * 32 + lk];
      bf16x8 b1 = *(const bf16x8*)&Bl[wn * 32 + 16 + lr][kc * 32 + lk];
      acc[0][0] = __builtin_amdgcn_mfma_f32_16x16x32_bf16(a0, b0, acc[0][0], 0, 0, 0);
      acc[0][1] = __builtin_amdgcn_mfma_f32_16x16x32_bf16(a0, b1, acc[0][1], 0, 0, 0);
      acc[1][0] = __builtin_amdgcn_mfma_f32_16x16x32_bf16(a1, b0, acc[1][0], 0, 0, 0);
      acc[1][1] = __builtin_amdgcn_mfma_f32_16x16x32_bf16(a1, b1, acc[1][1], 0, 0, 0);
    }
    __syncthreads();
  }

#pragma unroll
  for (int mi = 0; mi < 2; ++mi)
#pragma unroll
    for (int ni = 0; ni < 2; ++ni)
#pragma unroll
      for (int e = 0; e < 4; ++e) {
        int row = bm0 + wm * 32 + mi * 16 + ((lane >> 4) << 2) + e;
        int col = bn0 + wn * 32 + ni * 16 + lr;
        float v = acc[mi][ni][e];
        if (BIAS)  v += bias[col];
        if (RESID) v += resid[(size_t)row * N + col];
        if (GELU)  v = gelu_f(v);
        if (ACCUM) v += outf[(size_t)row * N + col];
        if (OUTF)  outf[(size_t)row * N + col] = v;
        if (OUTB) {
          if (TROUT) outb[(size_t)col * M + row] = (__bf16)v;
          else       outb[(size_t)row * N + col] = (__bf16)v;
        }
      }
}

__global__ __launch_bounds__(256) void copy_out(const float* __restrict__ z, float* __restrict__ out) {
  int i = blockIdx.x * 256 + threadIdx.x;
  out[i] = z[i];
}

extern "C" void kernel_launch(void* const* d_in, const int* in_sizes, int n_in,
                              void* d_out, int out_size, void* d_ws, size_t ws_size,
                              hipStream_t stream) {
  const float* x_encoded = (const float*)d_in[0];
  const float* y_current = (const float*)d_in[1];
  const float* Wpi  = (const float*)d_in[2];
  const float* bpi  = (const float*)d_in[3];
  const float* Wpa  = (const float*)d_in[4];
  const float* bpa  = (const float*)d_in[5];
  const float* Wc   = (const float*)d_in[6];
  const float* bc   = (const float*)d_in[7];
  const float* ln1g = (const float*)d_in[8];
  const float* ln1b = (const float*)d_in[9];
  const float* wqkv = (const float*)d_in[10];
  const float* bqkv = (const float*)d_in[11];
  const float* wo   = (const float*)d_in[12];
  const float* bo   = (const float*)d_in[13];
  const float* ln2g = (const float*)d_in[14];
  const float* ln2b = (const float*)d_in[15];
  const float* w1f  = (const float*)d_in[16];
  const float* b1f  = (const float*)d_in[17];
  const float* w2f  = (const float*)d_in[18];
  const float* b2f  = (const float*)d_in[19];
  (void)in_sizes; (void)n_in; (void)out_size; (void)ws_size;

  char* wsb = (char*)d_ws;
  size_t off = 0;
  auto carve = [&](size_t bytes) -> void* {
    void* p = wsb + off;
    off += (bytes + 255) & ~(size_t)255;
    return p;
  };
  float*  xp_f    = (float*) carve(131072 * 4);
  __bf16* xp_b    = (__bf16*)carve(131072 * 2);
  __bf16* y_b     = (__bf16*)carve(32768 * 2);
  __bf16* WpiT    = (__bf16*)carve(524288 * 2);
  __bf16* WpaT    = (__bf16*)carve(131072 * 2);
  __bf16* WcaT    = (__bf16*)carve(262144 * 2);
  __bf16* WcbT    = (__bf16*)carve(262144 * 2);
  __bf16* WccT    = (__bf16*)carve(262144 * 2);
  __bf16* w1T     = (__bf16*)carve(2097152 * 2);
  __bf16* w2T     = (__bf16*)carve(2097152 * 2);
  __bf16* woT     = (__bf16*)carve(524288 * 2);
  __bf16* Wv_b    = (__bf16*)carve(524288 * 2);
  __bf16* WeffT   = (__bf16*)carve(524288 * 2);
  float*  beff    = (float*) carve(1024 * 4);
  __bf16* xproj_b = (__bf16*)carve(65536 * 2);
  __bf16* yproj_b = (__bf16*)carve(65536 * 2);
  float*  base_f  = (float*) carve(65536 * 4);
  float*  z_f     = (float*) carve(65536 * 4);
  __bf16* z_b     = (__bf16*)carve(65536 * 2);
  float*  c_f     = (float*) carve(65536 * 4);
  __bf16* c_b     = (__bf16*)carve(65536 * 2);
  float*  x_f     = (float*) carve(65536 * 4);
  __bf16* xbA     = (__bf16*)carve(65536 * 2);
  __bf16* xbB     = (__bf16*)carve(65536 * 2);
  __bf16* u_b     = (__bf16*)carve(262144 * 2);

  pool_kernel<<<dim3(4, 128), 256, 0, stream>>>(x_encoded, xp_f, xp_b);
  transpose_batch<<<6016, 256, 0, stream>>>(Wpi, Wpa, Wc, w1f, w2f, wo,
      WpiT, WpaT, WcaT, WcbT, WccT, w1T, w2T, woT);
  misc_convert<<<2688, 256, 0, stream>>>(wqkv, y_current, Wv_b, y_b, z_f, z_b);
  beff_kernel<<<dim3(2, 2), 256, 0, stream>>>(bqkv, wo, bo, beff);

  // WeffT[l] = (Wv[l] @ wo[l])^T  (output stored transposed, bf16)
  for (int l = 0; l < 2; ++l)
    gemm_stage<false,false,false,false,false,false,true,true>
      <<<dim3(8, 8), 256, 0, stream>>>(Wv_b + l * 262144, woT + l * 262144,
          nullptr, nullptr, nullptr, nullptr, nullptr, WeffT + l * 262144, 512, 512, 512);

  // xproj_b = bf16(x_pooled @ Wpi + bpi); yproj_b = bf16(y @ Wpa + bpa)
  gemm_stage<false,false,false,false,true,false,true,false>
    <<<dim3(8, 2), 256, 0, stream>>>(xp_b, WpiT, nullptr, nullptr, bpi, nullptr,
        nullptr, xproj_b, 128, 512, 1024);
  gemm_stage<false,false,false,false,true,false,true,false>
    <<<dim3(8, 2), 256, 0, stream>>>(y_b, WpaT, nullptr, nullptr, bpa, nullptr,
        nullptr, yproj_b, 128, 512, 256);
  // base = xproj @ Wc_a + bc ; base += yproj @ Wc_b
  gemm_stage<false,false,false,false,true,true,false,false>
    <<<dim3(8, 2), 256, 0, stream>>>(xproj_b, WcaT, nullptr, nullptr, bc, nullptr,
        base_f, nullptr, 128, 512, 512);
  gemm_stage<false,false,false,true,false,true,false,false>
    <<<dim3(8, 2), 256, 0, stream>>>(yproj_b, WcbT, nullptr, nullptr, nullptr, nullptr,
        base_f, nullptr, 128, 512, 512);

  for (int r = 0; r < 6; ++r) {
    // S1: c = base + z @ Wc_c
    gemm_stage<false,false,true,false,false,true,true,false>
      <<<dim3(8, 2), 256, 0, stream>>>(z_b, WccT, nullptr, nullptr, nullptr, base_f,
          c_f, c_b, 128, 512, 512);

    const __bf16* Ab = c_b;
    const float*  Rf = c_f;
    __bf16* xb_out = xbA;
    for (int l = 0; l < 2; ++l) {
      // S2: x = resid + LN(A;ln1) @ Weff + beff
      gemm_stage<true,false,true,false,true,true,true,false>
        <<<dim3(8, 2), 256, 0, stream>>>(Ab, WeffT + l * 262144,
            ln1g + l * 512, ln1b + l * 512, beff + l * 512, Rf, x_f, xb_out, 128, 512, 512);
      // S3: u = gelu(LN(x;ln2) @ w1 + b1)
      gemm_stage<true,true,false,false,true,false,true,false>
        <<<dim3(32, 2), 256, 0, stream>>>(xb_out, w1T + l * 1048576,
            ln2g + l * 512, ln2b + l * 512, b1f + l * 2048, nullptr, nullptr, u_b, 128, 2048, 512);
      // S4: x = x + u @ w2 + b2   (last block: z += that, write z_b)
      if (l == 0) {
        gemm_stage<false,false,true,false,true,true,true,false>
          <<<dim3(8, 2), 256, 0, stream>>>(u_b, w2T + l * 1048576,
              nullptr, nullptr, b2f + l * 512, x_f, x_f, xbB, 128, 512, 2048);
        Ab = xbB; Rf = x_f; xb_out = xbA;
      } else {
        gemm_stage<false,false,true,true,true,true,true,false>
          <<<dim3(8, 2), 256, 0, stream>>>(u_b, w2T + l * 1048576,
              nullptr, nullptr, b2f + l * 512, x_f, z_f, z_b, 128, 512, 2048);
      }
    }
  }

  copy_out<<<256, 256, 0, stream>>>(z_f, (float*)d_out);
}